// Round 7
// baseline (101.388 us; speedup 1.0000x reference)
//
#include <hip/hip_runtime.h>
#include <hip/hip_bf16.h>

#define BATCH    8192
#define NF       39      // num_fields
#define ED       64      // embed dim
#define RANK     32
#define KST      72      // f16 LDS k-stride in halves (144 B): conflict-free for b128 r/w
#define NFRAG    15      // 5 l-slices x 3 k-chunks
#define NEMB     100000
#define EMB_OFF  16384   // byte offset of f16 embed copy inside d_ws (wsW = 15360 B first)

typedef _Float16       half8   __attribute__((ext_vector_type(8)));
typedef unsigned short ushort8 __attribute__((ext_vector_type(8)));
typedef float          f32x16  __attribute__((ext_vector_type(16)));

// ---- prep: (a) f16 copy of embed table (streamed, lands in L3 behind the
// harness's L3-flushing ws-fill); (b) 15 W A-fragments in per-lane MFMA layout.
__global__ void prep(const float* __restrict__ embed,
                     const float* __restrict__ W0,
                     const float* __restrict__ W1,
                     _Float16* __restrict__ embh,    // (NEMB, 64)
                     half8* __restrict__ wsW) {
    if (blockIdx.x < 3125) {
        // 3125 blocks x 256 threads x 8 elem = 6.4e6 = NEMB*ED
        int d = (blockIdx.x * 256 + threadIdx.x) * 8;
        float4 a = *(const float4*)(embed + d);
        float4 b = *(const float4*)(embed + d + 4);
        half8 h;
        h[0] = (_Float16)a.x; h[1] = (_Float16)a.y; h[2] = (_Float16)a.z; h[3] = (_Float16)a.w;
        h[4] = (_Float16)b.x; h[5] = (_Float16)b.y; h[6] = (_Float16)b.z; h[7] = (_Float16)b.w;
        *(half8*)(embh + d) = h;
    } else {
        // one block handles the 960 W fragments (4 iters of 256)
        for (int d = threadIdx.x; d < NFRAG * 64; d += 256) {
            int fid  = d >> 6;
            int lane = d & 63;
            int l = fid / 3, kc = fid % 3;
            int j = lane & 31, kh = lane >> 5;
            const float* base = (l < 2) ? (W0 + (l * RANK + j) * NF)
                                        : (W1 + ((l - 2) * RANK + j) * NF);
            half8 h;
#pragma unroll
            for (int e = 0; e < 8; ++e) {
                int k = kc * 16 + kh * 8 + e;
                h[e] = (k < NF) ? (_Float16)base[k] : (_Float16)0.0f;
            }
            wsW[d] = h;
        }
    }
}

// ---- main: one wave = one sample; gathers hit the L3-resident f16 table ----
__global__ __launch_bounds__(256, 3) void tfm_kernel(
    const int*      __restrict__ x,      // (B, NF)
    const _Float16* __restrict__ embh,   // (NEMB, 64) f16
    const float*    __restrict__ linw,   // (NEMB, 1)
    const float*    __restrict__ lbias,  // (1,)
    const half8*    __restrict__ wsW,    // [NFRAG][64]
    float*          __restrict__ out)    // (B,)
{
    __shared__ __align__(16) _Float16 Ws[NFRAG * 64 * 8];   // 15360 B
    __shared__ __align__(16) _Float16 Ef[4][ED][KST];       // 36864 B

    const int t    = threadIdx.x;
    const int lane = t & 63;
    const int w    = t >> 6;
    const int s    = blockIdx.x * 4 + w;     // one sample per wave

    const int j  = lane & 31;
    const int kh = lane >> 5;

    // ---- issue the gather chain first ----
    const int xi_v = (lane < NF) ? x[s * NF + lane] : 0;
    const float lv = (lane < NF) ? linw[xi_v] : 0.0f;

    const unsigned short* eh = (const unsigned short*)embh;
    unsigned short r[NF];
#pragma unroll
    for (int k = 0; k < NF; ++k) {
        int xi = __builtin_amdgcn_readlane(xi_v, k);   // uniform -> SGPR base
        r[k] = eh[(size_t)xi * ED + lane];             // one 128B line per instr
    }

    // ---- stage W frags into LDS (overlaps the gather) ----
    {
        const uint4* src = (const uint4*)wsW;
        uint4*       dst = (uint4*)Ws;
#pragma unroll
        for (int i = 0; i < NFRAG * 64 / 256; ++i)
            dst[i * 256 + t] = src[i * 256 + t];
        if (t < NFRAG * 64 - 768) dst[768 + t] = src[768 + t];
    }

    const float bias = lbias[0];

    // ---- pack halves along k (lane = embed column), 6 x b128, wave-private ----
#pragma unroll
    for (int c6 = 0; c6 < 6; ++c6) {
        ushort8 u;
#pragma unroll
        for (int e = 0; e < 8; ++e) {
            int k = c6 * 8 + e;
            u[e] = (k < NF) ? r[k] : (unsigned short)0;
        }
        *(ushort8*)&Ef[w][lane][c6 * 8] = u;
    }

    __syncthreads();   // Ws visible block-wide (Ef is wave-private)

    const half8* Wf = (const half8*)Ws;
    float ssum = lv;

#pragma unroll
    for (int tile = 0; tile < 2; ++tile) {
        const int c = tile * 32 + j;
        half8 bf[3];
#pragma unroll
        for (int kc = 0; kc < 3; ++kc)
            bf[kc] = *(const half8*)&Ef[w][c][kc * 16 + kh * 8];

        // phase W0: 2 accumulators, folded immediately
        {
            f32x16 a0, a1;
#pragma unroll
            for (int e = 0; e < 16; ++e) { a0[e] = 0.0f; a1[e] = 0.0f; }
#pragma unroll
            for (int kc = 0; kc < 3; ++kc) {
                a0 = __builtin_amdgcn_mfma_f32_32x32x16_f16(Wf[(0 * 3 + kc) * 64 + lane], bf[kc], a0, 0, 0, 0);
                a1 = __builtin_amdgcn_mfma_f32_32x32x16_f16(Wf[(1 * 3 + kc) * 64 + lane], bf[kc], a1, 0, 0, 0);
            }
#pragma unroll
            for (int e = 0; e < 16; ++e) ssum += a0[e] * a1[e];
        }
        // phase W1: 3 accumulators (reuses W0's registers)
        {
            f32x16 c0, c1, c2;
#pragma unroll
            for (int e = 0; e < 16; ++e) { c0[e] = 0.0f; c1[e] = 0.0f; c2[e] = 0.0f; }
#pragma unroll
            for (int kc = 0; kc < 3; ++kc) {
                c0 = __builtin_amdgcn_mfma_f32_32x32x16_f16(Wf[(2 * 3 + kc) * 64 + lane], bf[kc], c0, 0, 0, 0);
                c1 = __builtin_amdgcn_mfma_f32_32x32x16_f16(Wf[(3 * 3 + kc) * 64 + lane], bf[kc], c1, 0, 0, 0);
                c2 = __builtin_amdgcn_mfma_f32_32x32x16_f16(Wf[(4 * 3 + kc) * 64 + lane], bf[kc], c2, 0, 0, 0);
            }
#pragma unroll
            for (int e = 0; e < 16; ++e) ssum += c0[e] * c1[e] * c2[e];
        }
    }

    // ---- 64-lane reduce, lane 0 writes ----
#pragma unroll
    for (int off = 32; off > 0; off >>= 1) ssum += __shfl_down(ssum, off, 64);
    if (lane == 0) out[s] = ssum + bias;
}

extern "C" void kernel_launch(void* const* d_in, const int* in_sizes, int n_in,
                              void* d_out, int out_size, void* d_ws, size_t ws_size,
                              hipStream_t stream) {
    const int*   x     = (const int*)  d_in[0];
    const float* embed = (const float*)d_in[1];
    const float* linw  = (const float*)d_in[2];
    const float* lbias = (const float*)d_in[3];
    const float* W0    = (const float*)d_in[4];
    const float* W1    = (const float*)d_in[5];
    float*       out   = (float*)d_out;

    half8*    wsW  = (half8*)d_ws;                        // 15360 B
    _Float16* embh = (_Float16*)((char*)d_ws + EMB_OFF);  // 12.8 MB

    prep<<<3126, 256, 0, stream>>>(embed, W0, W1, embh, wsW);
    // 2048 blocks x 4 waves x 1 sample = 8192
    tfm_kernel<<<BATCH / 4, 256, 0, stream>>>(x, embh, linw, lbias, wsW, out);
}